// Round 1
// baseline (362.639 us; speedup 1.0000x reference)
//
#include <hip/hip_runtime.h>

typedef unsigned short u16;
typedef unsigned int u32;
typedef __attribute__((ext_vector_type(8))) short short8;
typedef __attribute__((ext_vector_type(4))) float f32x4;

// ---------------- helpers ----------------
__device__ __forceinline__ u16 f2bf(float f) {
    unsigned int u = __float_as_uint(f);
    u += 0x7fffu + ((u >> 16) & 1u);   // round-to-nearest-even
    return (u16)(u >> 16);
}

// pack two f32 -> two truncated bf16 in one u32: low16 = hi16(a), high16 = hi16(b)
__device__ __forceinline__ u32 pack_trunc(float a, float b) {
    return __builtin_amdgcn_perm(__float_as_uint(b), __float_as_uint(a), 0x07060302u);
}

// async global->LDS, 16B per lane. LDS dest = wave-uniform base + lane*16.
__device__ __forceinline__ void gload16(const u16* g, const u16* l) {
    __builtin_amdgcn_global_load_lds(
        (const __attribute__((address_space(1))) unsigned int*)g,
        (__attribute__((address_space(3))) unsigned int*)l, 16, 0, 0);
}

// ---------------- fused cast fp32 -> bf16 (all 7 tensors, one launch) ----------------
__global__ __launch_bounds__(256) void cast_all(const float* __restrict__ k,
                                                const float* __restrict__ q,
                                                const float* __restrict__ v,
                                                const float* __restrict__ wk,
                                                const float* __restrict__ wq,
                                                const float* __restrict__ wv,
                                                const float* __restrict__ wo,
                                                u16* __restrict__ Xk, u16* __restrict__ Xq,
                                                u16* __restrict__ Xv, u16* __restrict__ Wk,
                                                u16* __restrict__ Wq, u16* __restrict__ Wv,
                                                u16* __restrict__ Wo) {
    size_t i = ((size_t)blockIdx.x * 256 + threadIdx.x) * 8;
    const float* src; u16* dst; size_t off;
    if (i < 25165824) {                       // 3 x 2^23 activations
        int r = (int)(i >> 23); off = i & 8388607;
        src = r == 0 ? k : (r == 1 ? q : v);
        dst = r == 0 ? Xk : (r == 1 ? Xq : Xv);
    } else {                                  // 4 x 2^20 weights
        size_t j = i - 25165824;
        int r = (int)(j >> 20); off = j & 1048575;
        src = r == 0 ? wk : (r == 1 ? wq : (r == 2 ? wv : wo));
        dst = r == 0 ? Wk : (r == 1 ? Wq : (r == 2 ? Wv : Wo));
    }
    float4 a = *(const float4*)(src + off);
    float4 b = *(const float4*)(src + off + 4);
    union { u16 h[8]; uint4 u; } r8;
    r8.h[0] = f2bf(a.x); r8.h[1] = f2bf(a.y); r8.h[2] = f2bf(a.z); r8.h[3] = f2bf(a.w);
    r8.h[4] = f2bf(b.x); r8.h[5] = f2bf(b.y); r8.h[6] = f2bf(b.z); r8.h[7] = f2bf(b.w);
    *(uint4*)(dst + off) = r8.u;
}

// ---------------- batched QKV GEMM, XCD-swizzled 1-D grid (1536 blocks) ----------------
// flat f: z = f>>9; within z: XCD = i&7 = f&7, j = (f>>3)&7, i-high = (f>>6)&7.
// All 8 j-tiles sharing an X-row-block land on one XCD -> X rows hit that L2 once.
//
// v2: (a) double-buffered LDS + prefetch: issue next K-step's global_load_lds BEFORE
//     computing the current one; single barrier/iter (its implicit vmcnt(0) drains the
//     prefetch). Load latency hides under ds_read+MFMA instead of a dead drain.
//     (b) bank-conflict swizzle, both-sides (rule #21): LDS stays linear (gload_lds
//     requirement), global SOURCE column is pre-swizzled seg^=(row>>1)&3 (16B units),
//     fragment reads use col quad^((l16>>1)&3). 16 lanes spread over 8 bank-groups.
__global__ __launch_bounds__(256) void gemm_qkv(const u16* __restrict__ Xk,
                                                const u16* __restrict__ Xq,
                                                const u16* __restrict__ Xv,
                                                const u16* __restrict__ Wk,
                                                const u16* __restrict__ Wq,
                                                const u16* __restrict__ Wv,
                                                const float* __restrict__ bK,
                                                const float* __restrict__ bQ,
                                                const float* __restrict__ bV,
                                                u16* __restrict__ Kbh,
                                                u16* __restrict__ Qbh,
                                                u16* __restrict__ Vtg,
                                                float kscale) {
    __shared__ u16 sA[2 * 128 * 32];
    __shared__ u16 sB[2 * 128 * 32];
    const int f = blockIdx.x;
    const int z = f >> 9;
    const int r9 = f & 511;
    const int i_idx = (r9 & 7) | (((r9 >> 6) & 7) << 3);
    const int j_idx = (r9 >> 3) & 7;

    const u16* X = z == 0 ? Xk : (z == 1 ? Xq : Xv);
    const u16* W = z == 0 ? Wk : (z == 1 ? Wq : Wv);
    const float* bias = z == 0 ? bK : (z == 1 ? bQ : bV);
    u16* out = z == 0 ? Kbh : (z == 1 ? Qbh : Vtg);
    const float scale = z == 0 ? kscale : 1.0f;

    const int tid  = threadIdx.x;
    const int wave = tid >> 6, lane = tid & 63;
    const int quad = lane >> 4, l16 = lane & 15;
    const int wm = wave & 1, wn = wave >> 1;
    const int i0 = i_idx * 128, j0 = j_idx * 128;
    const int lrow = tid >> 2;
    // swizzled source column: LDS slot (row, c) must hold data(row, c ^ ((row>>1)&3))
    const int lseg = (tid & 3) ^ ((tid >> 3) & 3);
    const int sw   = (l16 >> 1) & 3;   // read-side XOR

    f32x4 acc[4][4];
    #pragma unroll
    for (int mt = 0; mt < 4; mt++)
        #pragma unroll
        for (int nt = 0; nt < 4; nt++) acc[mt][nt] = (f32x4){0.f, 0.f, 0.f, 0.f};

    const u16* gA0 = X + (size_t)(i0 + lrow) * 1024 + lseg * 8;
    const u16* gA1 = X + (size_t)(i0 + 64 + lrow) * 1024 + lseg * 8;
    const u16* gB0 = W + (size_t)(j0 + lrow) * 1024 + lseg * 8;
    const u16* gB1 = W + (size_t)(j0 + 64 + lrow) * 1024 + lseg * 8;

    auto stage = [&](int buf, int kk) {
        const u16* a = sA + buf * 4096 + wave * 512;
        const u16* b = sB + buf * 4096 + wave * 512;
        gload16(gA0 + kk, a);
        gload16(gA1 + kk, a + 2048);
        gload16(gB0 + kk, b);
        gload16(gB1 + kk, b + 2048);
    };

    stage(0, 0);
    __syncthreads();          // implicit vmcnt(0): buf0 ready
    int cur = 0;

    for (int kk = 0; kk < 1024; kk += 32) {
        if (kk + 32 < 1024) stage(cur ^ 1, kk + 32);   // prefetch next K-step
        const u16* bA = sA + cur * 4096;
        const u16* bB = sB + cur * 4096;
        short8 af[4], bf[4];
        #pragma unroll
        for (int mt = 0; mt < 4; mt++)
            af[mt] = *(const short8*)&bA[(wm * 64 + mt * 16 + l16) * 32 + (quad ^ sw) * 8];
        #pragma unroll
        for (int nt = 0; nt < 4; nt++)
            bf[nt] = *(const short8*)&bB[(wn * 64 + nt * 16 + l16) * 32 + (quad ^ sw) * 8];
        #pragma unroll
        for (int mt = 0; mt < 4; mt++)
            #pragma unroll
            for (int nt = 0; nt < 4; nt++)
                acc[mt][nt] = __builtin_amdgcn_mfma_f32_16x16x32_bf16(af[mt], bf[nt], acc[mt][nt], 0, 0, 0);
        __syncthreads();      // drains prefetch (vmcnt 0) + guards LDS reuse
        cur ^= 1;
    }

    #pragma unroll
    for (int mt = 0; mt < 4; mt++) {
        #pragma unroll
        for (int nt = 0; nt < 4; nt++) {
            int j = j0 + wn * 64 + nt * 16 + l16;
            float bj = bias[j];
            #pragma unroll
            for (int r = 0; r < 4; r++) {
                int i = i0 + wm * 64 + mt * 16 + quad * 4 + r;
                float v = (acc[mt][nt][r] + bj) * scale;
                int b = i >> 11, t = i & 2047;
                int h = j >> 6,  dd = j & 63;
                size_t idx;
                if (z == 2) idx = (((size_t)(b * 16 + h)) * 64 + dd) * 2048 + t;
                else        idx = (((size_t)(b * 16 + h)) * 2048 + t) * 64 + dd;
                out[idx] = f2bf(v);
            }
        }
    }
}

// ---------------- output GEMM: 128x64 tile, XCD-swizzled (1024 blocks) ----------------
// XCD = i&7 = f&7; j = (f>>3)&15; i-high = f>>7. ctx row-block pinned to one XCD L2.
// v2: same double-buffer prefetch + source-side bank swizzle as gemm_qkv.
__global__ __launch_bounds__(256) void gemm_out(const u16* __restrict__ X,
                                                const u16* __restrict__ W,
                                                const float* __restrict__ bias,
                                                float* __restrict__ out) {
    __shared__ u16 sA[2 * 128 * 32];
    __shared__ u16 sB[2 * 64 * 32];
    const int f = blockIdx.x;
    const int j_idx = (f >> 3) & 15;
    const int i_idx = (f & 7) | ((f >> 7) << 3);
    const int tid  = threadIdx.x;
    const int wave = tid >> 6, lane = tid & 63;
    const int quad = lane >> 4, l16 = lane & 15;
    const int wm = wave & 1, wn = wave >> 1;
    const int i0 = i_idx * 128, j0 = j_idx * 64;
    const int lrow = tid >> 2;
    const int lseg = (tid & 3) ^ ((tid >> 3) & 3);
    const int sw   = (l16 >> 1) & 3;

    f32x4 acc[4][2];
    #pragma unroll
    for (int mt = 0; mt < 4; mt++) {
        acc[mt][0] = (f32x4){0.f, 0.f, 0.f, 0.f};
        acc[mt][1] = (f32x4){0.f, 0.f, 0.f, 0.f};
    }

    const u16* gA0 = X + (size_t)(i0 + lrow) * 1024 + lseg * 8;
    const u16* gA1 = X + (size_t)(i0 + 64 + lrow) * 1024 + lseg * 8;
    const u16* gB0 = W + (size_t)(j0 + lrow) * 1024 + lseg * 8;

    auto stage = [&](int buf, int kk) {
        const u16* a = sA + buf * 4096 + wave * 512;
        const u16* b = sB + buf * 2048 + wave * 512;
        gload16(gA0 + kk, a);
        gload16(gA1 + kk, a + 2048);
        gload16(gB0 + kk, b);
    };

    stage(0, 0);
    __syncthreads();
    int cur = 0;

    for (int kk = 0; kk < 1024; kk += 32) {
        if (kk + 32 < 1024) stage(cur ^ 1, kk + 32);
        const u16* bA = sA + cur * 4096;
        const u16* bB = sB + cur * 2048;
        short8 af[4], bf[2];
        #pragma unroll
        for (int mt = 0; mt < 4; mt++)
            af[mt] = *(const short8*)&bA[(wm * 64 + mt * 16 + l16) * 32 + (quad ^ sw) * 8];
        #pragma unroll
        for (int nt = 0; nt < 2; nt++)
            bf[nt] = *(const short8*)&bB[(wn * 32 + nt * 16 + l16) * 32 + (quad ^ sw) * 8];
        #pragma unroll
        for (int mt = 0; mt < 4; mt++)
            #pragma unroll
            for (int nt = 0; nt < 2; nt++)
                acc[mt][nt] = __builtin_amdgcn_mfma_f32_16x16x32_bf16(af[mt], bf[nt], acc[mt][nt], 0, 0, 0);
        __syncthreads();
        cur ^= 1;
    }

    #pragma unroll
    for (int mt = 0; mt < 4; mt++) {
        #pragma unroll
        for (int nt = 0; nt < 2; nt++) {
            int j = j0 + wn * 32 + nt * 16 + l16;
            float bj = bias[j];
            #pragma unroll
            for (int r = 0; r < 4; r++) {
                int i = i0 + wm * 64 + mt * 16 + quad * 4 + r;
                out[(size_t)i * 1024 + j] = acc[mt][nt][r] + bj;
            }
        }
    }
}

// ---------------- flash attention v4 + XCD swizzle (512 blocks) ----------------
// XCD = bh&7 = f&7; tx = (f>>3)&7; bh-high = f>>6. A head's Q/V^T stay in one L2.
#define QST 72   // LDS row stride in u16

__global__ __launch_bounds__(256, 2) void attn_kernel(const u16* __restrict__ Kbh,
                                                      const u16* __restrict__ Qbh,
                                                      const u16* __restrict__ Vtg,
                                                      u16* __restrict__ ctx) {
    __shared__ u16 sQ[64 * QST];             // [s_local][dk]
    __shared__ u16 sVt[64 * QST];            // [dk][s_local]
    __shared__ u16 sP[4 * 2 * 16 * QST];     // [wave][buf][t16][s64]
    const int f = blockIdx.x;
    const int bh = (f & 7) | ((f >> 6) << 3);
    const int tx = (f >> 3) & 7;
    const int tid  = threadIdx.x;
    const int wave = tid >> 6, lane = tid & 63;
    const int quad = lane >> 4, l16 = lane & 15;
    const int t0 = tx * 256;
    const int tw = t0 + wave * 64;
    const size_t base = (size_t)bh * 2048 * 64;

    // K as B-fragments, 4 t-groups x 2 dk-chunks, held in regs
    short8 bk[4][2];
    #pragma unroll
    for (int g = 0; g < 4; g++) {
        const u16* kr = Kbh + base + (size_t)(tw + g * 16 + l16) * 64 + quad * 8;
        bk[g][0] = *(const short8*)kr;
        bk[g][1] = *(const short8*)(kr + 32);
    }
    const short8 ones = {0x3F80, 0x3F80, 0x3F80, 0x3F80, 0x3F80, 0x3F80, 0x3F80, 0x3F80};

    f32x4 accO[4][4];
    #pragma unroll
    for (int g = 0; g < 4; g++)
        #pragma unroll
        for (int dt = 0; dt < 4; dt++) accO[g][dt] = (f32x4){0.f, 0.f, 0.f, 0.f};
    f32x4 accL[4];
    #pragma unroll
    for (int g = 0; g < 4; g++) accL[g] = (f32x4){0.f, 0.f, 0.f, 0.f};

    const int srow = tid >> 2, seg = tid & 3;
    u16* sPw = sP + wave * 2 * 16 * QST;

    for (int s0 = 0; s0 < 2048; s0 += 64) {
        __syncthreads();
        {   // stage Q chunk [s][dk]
            const uint4* gq = (const uint4*)(Qbh + base + (size_t)(s0 + srow) * 64 + seg * 16);
            uint4 q0 = gq[0], q1 = gq[1];
            *(uint4*)&sQ[srow * QST + seg * 16]     = q0;
            *(uint4*)&sQ[srow * QST + seg * 16 + 8] = q1;
        }
        {   // stage V^T chunk [dk][s]
            const uint4* gv = (const uint4*)(Vtg + ((size_t)bh * 64 + srow) * 2048 + s0 + seg * 16);
            uint4 v0 = gv[0], v1 = gv[1];
            *(uint4*)&sVt[srow * QST + seg * 16]     = v0;
            *(uint4*)&sVt[srow * QST + seg * 16 + 8] = v1;
        }
        __syncthreads();

        // cache Q A-frags and V^T A-frags once; reuse for all 4 t-groups
        short8 aq[4][2], av[2][4];
        #pragma unroll
        for (int nt = 0; nt < 4; nt++) {
            aq[nt][0] = *(const short8*)&sQ[(nt * 16 + l16) * QST + quad * 8];
            aq[nt][1] = *(const short8*)&sQ[(nt * 16 + l16) * QST + 32 + quad * 8];
        }
        #pragma unroll
        for (int kk = 0; kk < 2; kk++)
            #pragma unroll
            for (int dt = 0; dt < 4; dt++)
                av[kk][dt] = *(const short8*)&sVt[(dt * 16 + l16) * QST + kk * 32 + quad * 8];

        #pragma unroll
        for (int g = 0; g < 4; g++) {
            // S^T[s][t] for this group: A = Q (cached), B = K (regs)
            f32x4 aS[4];
            #pragma unroll
            for (int nt = 0; nt < 4; nt++) {
                f32x4 s = __builtin_amdgcn_mfma_f32_16x16x32_bf16(aq[nt][0], bk[g][0],
                            (f32x4){0.f, 0.f, 0.f, 0.f}, 0, 0, 0);
                aS[nt] = __builtin_amdgcn_mfma_f32_16x16x32_bf16(aq[nt][1], bk[g][1], s, 0, 0, 0);
            }
            // P^T = 2^(S^T): raw v_exp_f32, truncate-pack to bf16 pairs
            u16* pb = sPw + (g & 1) * 16 * QST;
            #pragma unroll
            for (int nt = 0; nt < 4; nt++) {
                float p0 = __builtin_amdgcn_exp2f(aS[nt][0]);
                float p1 = __builtin_amdgcn_exp2f(aS[nt][1]);
                float p2 = __builtin_amdgcn_exp2f(aS[nt][2]);
                float p3 = __builtin_amdgcn_exp2f(aS[nt][3]);
                uint2 pk = { pack_trunc(p0, p1), pack_trunc(p2, p3) };
                *(uint2*)&pb[l16 * QST + nt * 16 + quad * 4] = pk;
            }
            // O^T += V^T @ P^T ; L += ones @ P^T
            #pragma unroll
            for (int kk = 0; kk < 2; kk++) {
                short8 bp = *(const short8*)&pb[l16 * QST + kk * 32 + quad * 8];
                accL[g] = __builtin_amdgcn_mfma_f32_16x16x32_bf16(ones, bp, accL[g], 0, 0, 0);
                #pragma unroll
                for (int dt = 0; dt < 4; dt++)
                    accO[g][dt] = __builtin_amdgcn_mfma_f32_16x16x32_bf16(av[kk][dt], bp, accO[g][dt], 0, 0, 0);
            }
        }
    }

    // epilogue: lane holds col t = tw+g*16+l16, rows d = dt*16+quad*4+r
    const int b = bh >> 4, h = bh & 15;
    #pragma unroll
    for (int g = 0; g < 4; g++) {
        float inv = 1.f / accL[g][0];
        int t = tw + g * 16 + l16;
        u16* orow = ctx + ((size_t)(b * 2048 + t)) * 1024 + h * 64;
        #pragma unroll
        for (int dt = 0; dt < 4; dt++) {
            union { u16 h4[4]; uint2 u; } o;
            #pragma unroll
            for (int r = 0; r < 4; r++) o.h4[r] = f2bf(accO[g][dt][r] * inv);
            *(uint2*)&orow[dt * 16 + quad * 4] = o.u;
        }
    }
}

// ---------------- launcher ----------------
extern "C" void kernel_launch(void* const* d_in, const int* in_sizes, int n_in,
                              void* d_out, int out_size, void* d_ws, size_t ws_size,
                              hipStream_t stream) {
    const float* keys    = (const float*)d_in[0];
    const float* queries = (const float*)d_in[1];
    const float* values  = (const float*)d_in[2];
    // d_in[3] = pad_mask (unused by the reference, faithfully ignored)
    const float* WKb = (const float*)d_in[5];
    const float* WQb = (const float*)d_in[7];
    const float* WVb = (const float*)d_in[9];
    const float* WOb = (const float*)d_in[11];

    char* ws = (char*)d_ws;
    const size_t MB = 1 << 20;
    u16* Kbh = (u16*)(ws + 0 * MB);
    u16* Qbh = (u16*)(ws + 16 * MB);
    u16* Vtg = (u16*)(ws + 32 * MB);
    u16* Xk  = (u16*)(ws + 48 * MB);
    u16* Xq  = (u16*)(ws + 64 * MB);
    u16* Xv  = (u16*)(ws + 80 * MB);
    u16* Wk  = (u16*)(ws + 96 * MB);
    u16* Wq  = (u16*)(ws + 98 * MB);
    u16* Wv  = (u16*)(ws + 100 * MB);
    u16* Wo  = (u16*)(ws + 102 * MB);
    u16* ctx = (u16*)(ws + 48 * MB);   // aliases Xk (dead after QKV projection)

    cast_all<<<14336, 256, 0, stream>>>(keys, queries, values,
                                        (const float*)d_in[4], (const float*)d_in[6],
                                        (const float*)d_in[8], (const float*)d_in[10],
                                        Xk, Xq, Xv, Wk, Wq, Wv, Wo);

    const float kscale = 1.4426950408889634f * 0.125f;  // log2(e)/sqrt(d_key)
    gemm_qkv<<<1536, 256, 0, stream>>>(Xk, Xq, Xv, Wk, Wq, Wv,
                                       WKb, WQb, WVb, Kbh, Qbh, Vtg, kscale);

    attn_kernel<<<512, 256, 0, stream>>>(Kbh, Qbh, Vtg, ctx);

    gemm_out<<<1024, 256, 0, stream>>>(ctx, Wo, WOb, (float*)d_out);
}

// Round 2
// 358.268 us; speedup vs baseline: 1.0122x; 1.0122x over previous
//
#include <hip/hip_runtime.h>

typedef unsigned short u16;
typedef unsigned int u32;
typedef __attribute__((ext_vector_type(8))) short short8;
typedef __attribute__((ext_vector_type(4))) float f32x4;

// ---------------- helpers ----------------
__device__ __forceinline__ u16 f2bf(float f) {
    unsigned int u = __float_as_uint(f);
    u += 0x7fffu + ((u >> 16) & 1u);   // round-to-nearest-even
    return (u16)(u >> 16);
}

__device__ __forceinline__ u32 pack_trunc(float a, float b) {
    return __builtin_amdgcn_perm(__float_as_uint(b), __float_as_uint(a), 0x07060302u);
}

// async global->LDS, 16B per lane. LDS dest = wave-uniform base + lane*16.
__device__ __forceinline__ void gload16(const u16* g, const u16* l) {
    __builtin_amdgcn_global_load_lds(
        (const __attribute__((address_space(1))) unsigned int*)g,
        (__attribute__((address_space(3))) unsigned int*)l, 16, 0, 0);
}

// ---------------- fused cast fp32 -> bf16 (all 7 tensors, one launch) ----------------
__global__ __launch_bounds__(256) void cast_all(const float* __restrict__ k,
                                                const float* __restrict__ q,
                                                const float* __restrict__ v,
                                                const float* __restrict__ wk,
                                                const float* __restrict__ wq,
                                                const float* __restrict__ wv,
                                                const float* __restrict__ wo,
                                                u16* __restrict__ Xk, u16* __restrict__ Xq,
                                                u16* __restrict__ Xv, u16* __restrict__ Wk,
                                                u16* __restrict__ Wq, u16* __restrict__ Wv,
                                                u16* __restrict__ Wo) {
    size_t i = ((size_t)blockIdx.x * 256 + threadIdx.x) * 8;
    const float* src; u16* dst; size_t off;
    if (i < 25165824) {                       // 3 x 2^23 activations
        int r = (int)(i >> 23); off = i & 8388607;
        src = r == 0 ? k : (r == 1 ? q : v);
        dst = r == 0 ? Xk : (r == 1 ? Xq : Xv);
    } else {                                  // 4 x 2^20 weights
        size_t j = i - 25165824;
        int r = (int)(j >> 20); off = j & 1048575;
        src = r == 0 ? wk : (r == 1 ? wq : (r == 2 ? wv : wo));
        dst = r == 0 ? Wk : (r == 1 ? Wq : (r == 2 ? Wv : Wo));
    }
    float4 a = *(const float4*)(src + off);
    float4 b = *(const float4*)(src + off + 4);
    union { u16 h[8]; uint4 u; } r8;
    r8.h[0] = f2bf(a.x); r8.h[1] = f2bf(a.y); r8.h[2] = f2bf(a.z); r8.h[3] = f2bf(a.w);
    r8.h[4] = f2bf(b.x); r8.h[5] = f2bf(b.y); r8.h[6] = f2bf(b.z); r8.h[7] = f2bf(b.w);
    *(uint4*)(dst + off) = r8.u;
}

// =====================================================================================
// v3 GEMM core: 256x128 tile, BK=64, 3-slot LDS ring (144KB dynamic), 512 thr = 8 waves
// (2M x 4N; per-wave C = 128x32 = acc[8][2]).
//
// Pipeline (counted vmcnt, never 0 in steady state):
//   prologue: stage tile0->slot0, tile1->slot1
//   body(t):  vmcnt(6)  [forces tile t landed; leaves tile t+1's 6 loads in flight]
//             barrier; ds_read frags + 32 MFMA/wave; barrier;
//             stage tile t+2 -> slot (t+2)%3        [6 gloads]
//   Stage-to-use gap = 2 full bodies (~1200cy) > HBM miss latency.
//
// Bank swizzle (rule #21, both-sides): LDS row = 128B = 8 x 16B slots; slot' = slot ^ (row&7).
//   - staging: gload_lds writes linearly; global SOURCE column = (tid&7) ^ ((tid>>3)&7)
//   - frag read: slot = (quad + kh*4) ^ (l16&7) -> 16 lanes span all 32 banks (2-way = free)
// =====================================================================================

// A slot: 256*64 u16 = 16384; B slot: 128*64 u16 = 8192.
__device__ __forceinline__ void stage_tile(const u16* __restrict__ X, const u16* __restrict__ W,
                                           int i0, int j0, int kt, u16* sA, u16* sB,
                                           int tid, int wave) {
    const int r = tid >> 3;
    const int sg = (tid & 7) ^ (r & 7);
    const u16* gA = X + (size_t)(i0 + r) * 1024 + kt + sg * 8;
    const u16* gB = W + (size_t)(j0 + r) * 1024 + kt + sg * 8;
    const u16* dA = sA + wave * 512;
    const u16* dB = sB + wave * 512;
    gload16(gA,               dA);
    gload16(gA + 64 * 1024,   dA + 4096);
    gload16(gA + 128 * 1024,  dA + 8192);
    gload16(gA + 192 * 1024,  dA + 12288);
    gload16(gB,               dB);
    gload16(gB + 64 * 1024,   dB + 4096);
}

__device__ __forceinline__ void tile_mfma(const u16* sA, const u16* sB,
                                          f32x4 (&acc)[8][2],
                                          int wm, int wn, int quad, int l16) {
    const int sx = l16 & 7;
    short8 bf[2][2];
    #pragma unroll
    for (int nf = 0; nf < 2; nf++)
        #pragma unroll
        for (int kh = 0; kh < 2; kh++) {
            int row = wn * 32 + nf * 16 + l16;
            int slot = (quad + kh * 4) ^ sx;
            bf[nf][kh] = *(const short8*)&sB[row * 64 + slot * 8];
        }
    #pragma unroll
    for (int mh = 0; mh < 2; mh++) {
        short8 af[4][2];
        #pragma unroll
        for (int mf = 0; mf < 4; mf++)
            #pragma unroll
            for (int kh = 0; kh < 2; kh++) {
                int row = wm * 128 + mh * 64 + mf * 16 + l16;
                int slot = (quad + kh * 4) ^ sx;
                af[mf][kh] = *(const short8*)&sA[row * 64 + slot * 8];
            }
        #pragma unroll
        for (int mf = 0; mf < 4; mf++)
            #pragma unroll
            for (int nf = 0; nf < 2; nf++)
                #pragma unroll
                for (int kh = 0; kh < 2; kh++)
                    acc[mh * 4 + mf][nf] = __builtin_amdgcn_mfma_f32_16x16x32_bf16(
                        af[mf][kh], bf[nf][kh], acc[mh * 4 + mf][nf], 0, 0, 0);
    }
}

#define GEMM_PIPELINE(X, W)                                                              \
    stage_tile(X, W, i0, j0, 0,  sAr,         sBr,        tid, wave);                    \
    stage_tile(X, W, i0, j0, 64, sAr + 16384, sBr + 8192, tid, wave);                    \
    int rs = 0;                                                                          \
    _Pragma("unroll 1")                                                                  \
    for (int t = 0; t < 14; t++) {                                                       \
        asm volatile("s_waitcnt vmcnt(6)" ::: "memory");                                 \
        __builtin_amdgcn_s_barrier();                                                    \
        __builtin_amdgcn_s_setprio(1);                                                   \
        tile_mfma(sAr + rs * 16384, sBr + rs * 8192, acc, wm, wn, quad, l16);            \
        __builtin_amdgcn_s_setprio(0);                                                   \
        __builtin_amdgcn_s_barrier();                                                    \
        int ss = rs + 2; if (ss >= 3) ss -= 3;                                           \
        stage_tile(X, W, i0, j0, (t + 2) * 64, sAr + ss * 16384, sBr + ss * 8192,        \
                   tid, wave);                                                           \
        rs = (rs == 2) ? 0 : rs + 1;                                                     \
    }                                                                                    \
    asm volatile("s_waitcnt vmcnt(6)" ::: "memory");   /* t=14: forces tile14 */          \
    __builtin_amdgcn_s_barrier();                                                        \
    tile_mfma(sAr + rs * 16384, sBr + rs * 8192, acc, wm, wn, quad, l16);                \
    __builtin_amdgcn_s_barrier();                                                        \
    rs = (rs == 2) ? 0 : rs + 1;                                                         \
    asm volatile("s_waitcnt vmcnt(0)" ::: "memory");   /* t=15: drain */                  \
    __builtin_amdgcn_s_barrier();                                                        \
    tile_mfma(sAr + rs * 16384, sBr + rs * 8192, acc, wm, wn, quad, l16);

// ---------------- batched QKV GEMM: 768 blocks (3 clean CU rounds), XCD-chunked -------
__global__ __launch_bounds__(512, 2) void gemm_qkv(const u16* __restrict__ Xk,
                                                   const u16* __restrict__ Xq,
                                                   const u16* __restrict__ Xv,
                                                   const u16* __restrict__ Wk,
                                                   const u16* __restrict__ Wq,
                                                   const u16* __restrict__ Wv,
                                                   const float* __restrict__ bK,
                                                   const float* __restrict__ bQ,
                                                   const float* __restrict__ bV,
                                                   u16* __restrict__ Kbh,
                                                   u16* __restrict__ Qbh,
                                                   u16* __restrict__ Vtg,
                                                   float kscale) {
    extern __shared__ __align__(16) u16 smem[];
    u16* sAr = smem;            // 3 * 16384
    u16* sBr = smem + 49152;    // 3 * 8192
    // bijective XCD chunking: 768 = 8 XCD * 96; within a chunk j varies fastest
    const int f  = blockIdx.x;
    const int wg = (f & 7) * 96 + (f >> 3);
    const int z  = wg >> 8;          // 3 z * 256 tiles
    const int r8 = wg & 255;
    const int i0 = (r8 >> 3) * 256;
    const int j0 = (r8 & 7) * 128;

    const u16* X = z == 0 ? Xk : (z == 1 ? Xq : Xv);
    const u16* W = z == 0 ? Wk : (z == 1 ? Wq : Wv);
    const float* bias = z == 0 ? bK : (z == 1 ? bQ : bV);
    u16* out = z == 0 ? Kbh : (z == 1 ? Qbh : Vtg);
    const float scale = z == 0 ? kscale : 1.0f;

    const int tid  = threadIdx.x;
    const int wave = tid >> 6, lane = tid & 63;
    const int quad = lane >> 4, l16 = lane & 15;
    const int wm = wave >> 2, wn = wave & 3;   // 2M x 4N

    f32x4 acc[8][2];
    #pragma unroll
    for (int m = 0; m < 8; m++) {
        acc[m][0] = (f32x4){0.f, 0.f, 0.f, 0.f};
        acc[m][1] = (f32x4){0.f, 0.f, 0.f, 0.f};
    }

    GEMM_PIPELINE(X, W)

    #pragma unroll
    for (int m = 0; m < 8; m++) {
        #pragma unroll
        for (int nf = 0; nf < 2; nf++) {
            int j = j0 + wn * 32 + nf * 16 + l16;
            float bj = bias[j];
            #pragma unroll
            for (int r = 0; r < 4; r++) {
                int i = i0 + wm * 128 + m * 16 + quad * 4 + r;
                float v = (acc[m][nf][r] + bj) * scale;
                int b = i >> 11, tt = i & 2047;
                int h = j >> 6,  dd = j & 63;
                size_t idx;
                if (z == 2) idx = (((size_t)(b * 16 + h)) * 64 + dd) * 2048 + tt;
                else        idx = (((size_t)(b * 16 + h)) * 2048 + tt) * 64 + dd;
                out[idx] = f2bf(v);
            }
        }
    }
}

// ---------------- output GEMM: 256 blocks (1 clean CU round), XCD-chunked -------------
__global__ __launch_bounds__(512, 2) void gemm_out(const u16* __restrict__ X,
                                                   const u16* __restrict__ W,
                                                   const float* __restrict__ bias,
                                                   float* __restrict__ out) {
    extern __shared__ __align__(16) u16 smem[];
    u16* sAr = smem;
    u16* sBr = smem + 49152;
    const int f  = blockIdx.x;
    const int wg = (f & 7) * 32 + (f >> 3);
    const int i0 = (wg >> 3) * 256;
    const int j0 = (wg & 7) * 128;

    const int tid  = threadIdx.x;
    const int wave = tid >> 6, lane = tid & 63;
    const int quad = lane >> 4, l16 = lane & 15;
    const int wm = wave >> 2, wn = wave & 3;

    f32x4 acc[8][2];
    #pragma unroll
    for (int m = 0; m < 8; m++) {
        acc[m][0] = (f32x4){0.f, 0.f, 0.f, 0.f};
        acc[m][1] = (f32x4){0.f, 0.f, 0.f, 0.f};
    }

    GEMM_PIPELINE(X, W)

    #pragma unroll
    for (int m = 0; m < 8; m++) {
        #pragma unroll
        for (int nf = 0; nf < 2; nf++) {
            int j = j0 + wn * 32 + nf * 16 + l16;
            float bj = bias[j];
            #pragma unroll
            for (int r = 0; r < 4; r++) {
                int i = i0 + wm * 128 + m * 16 + quad * 4 + r;
                out[(size_t)i * 1024 + j] = acc[m][nf][r] + bj;
            }
        }
    }
}

// ---------------- flash attention v4 + XCD swizzle (512 blocks) ----------------
#define QST 72   // LDS row stride in u16

__global__ __launch_bounds__(256, 2) void attn_kernel(const u16* __restrict__ Kbh,
                                                      const u16* __restrict__ Qbh,
                                                      const u16* __restrict__ Vtg,
                                                      u16* __restrict__ ctx) {
    __shared__ u16 sQ[64 * QST];             // [s_local][dk]
    __shared__ u16 sVt[64 * QST];            // [dk][s_local]
    __shared__ u16 sP[4 * 2 * 16 * QST];     // [wave][buf][t16][s64]
    const int f = blockIdx.x;
    const int bh = (f & 7) | ((f >> 6) << 3);
    const int tx = (f >> 3) & 7;
    const int tid  = threadIdx.x;
    const int wave = tid >> 6, lane = tid & 63;
    const int quad = lane >> 4, l16 = lane & 15;
    const int t0 = tx * 256;
    const int tw = t0 + wave * 64;
    const size_t base = (size_t)bh * 2048 * 64;

    short8 bk[4][2];
    #pragma unroll
    for (int g = 0; g < 4; g++) {
        const u16* kr = Kbh + base + (size_t)(tw + g * 16 + l16) * 64 + quad * 8;
        bk[g][0] = *(const short8*)kr;
        bk[g][1] = *(const short8*)(kr + 32);
    }
    const short8 ones = {0x3F80, 0x3F80, 0x3F80, 0x3F80, 0x3F80, 0x3F80, 0x3F80, 0x3F80};

    f32x4 accO[4][4];
    #pragma unroll
    for (int g = 0; g < 4; g++)
        #pragma unroll
        for (int dt = 0; dt < 4; dt++) accO[g][dt] = (f32x4){0.f, 0.f, 0.f, 0.f};
    f32x4 accL[4];
    #pragma unroll
    for (int g = 0; g < 4; g++) accL[g] = (f32x4){0.f, 0.f, 0.f, 0.f};

    const int srow = tid >> 2, seg = tid & 3;
    u16* sPw = sP + wave * 2 * 16 * QST;

    for (int s0 = 0; s0 < 2048; s0 += 64) {
        __syncthreads();
        {   // stage Q chunk [s][dk]
            const uint4* gq = (const uint4*)(Qbh + base + (size_t)(s0 + srow) * 64 + seg * 16);
            uint4 q0 = gq[0], q1 = gq[1];
            *(uint4*)&sQ[srow * QST + seg * 16]     = q0;
            *(uint4*)&sQ[srow * QST + seg * 16 + 8] = q1;
        }
        {   // stage V^T chunk [dk][s]
            const uint4* gv = (const uint4*)(Vtg + ((size_t)bh * 64 + srow) * 2048 + s0 + seg * 16);
            uint4 v0 = gv[0], v1 = gv[1];
            *(uint4*)&sVt[srow * QST + seg * 16]     = v0;
            *(uint4*)&sVt[srow * QST + seg * 16 + 8] = v1;
        }
        __syncthreads();

        short8 aq[4][2], av[2][4];
        #pragma unroll
        for (int nt = 0; nt < 4; nt++) {
            aq[nt][0] = *(const short8*)&sQ[(nt * 16 + l16) * QST + quad * 8];
            aq[nt][1] = *(const short8*)&sQ[(nt * 16 + l16) * QST + 32 + quad * 8];
        }
        #pragma unroll
        for (int kk = 0; kk < 2; kk++)
            #pragma unroll
            for (int dt = 0; dt < 4; dt++)
                av[kk][dt] = *(const short8*)&sVt[(dt * 16 + l16) * QST + kk * 32 + quad * 8];

        #pragma unroll
        for (int g = 0; g < 4; g++) {
            f32x4 aS[4];
            #pragma unroll
            for (int nt = 0; nt < 4; nt++) {
                f32x4 s = __builtin_amdgcn_mfma_f32_16x16x32_bf16(aq[nt][0], bk[g][0],
                            (f32x4){0.f, 0.f, 0.f, 0.f}, 0, 0, 0);
                aS[nt] = __builtin_amdgcn_mfma_f32_16x16x32_bf16(aq[nt][1], bk[g][1], s, 0, 0, 0);
            }
            u16* pb = sPw + (g & 1) * 16 * QST;
            #pragma unroll
            for (int nt = 0; nt < 4; nt++) {
                float p0 = __builtin_amdgcn_exp2f(aS[nt][0]);
                float p1 = __builtin_amdgcn_exp2f(aS[nt][1]);
                float p2 = __builtin_amdgcn_exp2f(aS[nt][2]);
                float p3 = __builtin_amdgcn_exp2f(aS[nt][3]);
                uint2 pk = { pack_trunc(p0, p1), pack_trunc(p2, p3) };
                *(uint2*)&pb[l16 * QST + nt * 16 + quad * 4] = pk;
            }
            #pragma unroll
            for (int kk = 0; kk < 2; kk++) {
                short8 bp = *(const short8*)&pb[l16 * QST + kk * 32 + quad * 8];
                accL[g] = __builtin_amdgcn_mfma_f32_16x16x32_bf16(ones, bp, accL[g], 0, 0, 0);
                #pragma unroll
                for (int dt = 0; dt < 4; dt++)
                    accO[g][dt] = __builtin_amdgcn_mfma_f32_16x16x32_bf16(av[kk][dt], bp, accO[g][dt], 0, 0, 0);
            }
        }
    }

    const int b = bh >> 4, h = bh & 15;
    #pragma unroll
    for (int g = 0; g < 4; g++) {
        float inv = 1.f / accL[g][0];
        int t = tw + g * 16 + l16;
        u16* orow = ctx + ((size_t)(b * 2048 + t)) * 1024 + h * 64;
        #pragma unroll
        for (int dt = 0; dt < 4; dt++) {
            union { u16 h4[4]; uint2 u; } o;
            #pragma unroll
            for (int r = 0; r < 4; r++) o.h4[r] = f2bf(accO[g][dt][r] * inv);
            *(uint2*)&orow[dt * 16 + quad * 4] = o.u;
        }
    }
}

// ---------------- launcher ----------------
extern "C" void kernel_launch(void* const* d_in, const int* in_sizes, int n_in,
                              void* d_out, int out_size, void* d_ws, size_t ws_size,
                              hipStream_t stream) {
    const float* keys    = (const float*)d_in[0];
    const float* queries = (const float*)d_in[1];
    const float* values  = (const float*)d_in[2];
    const float* WKb = (const float*)d_in[5];
    const float* WQb = (const float*)d_in[7];
    const float* WVb = (const float*)d_in[9];
    const float* WOb = (const float*)d_in[11];

    char* ws = (char*)d_ws;
    const size_t MB = 1 << 20;
    u16* Kbh = (u16*)(ws + 0 * MB);
    u16* Qbh = (u16*)(ws + 16 * MB);
    u16* Vtg = (u16*)(ws + 32 * MB);
    u16* Xk  = (u16*)(ws + 48 * MB);
    u16* Xq  = (u16*)(ws + 64 * MB);
    u16* Xv  = (u16*)(ws + 80 * MB);
    u16* Wk  = (u16*)(ws + 96 * MB);
    u16* Wq  = (u16*)(ws + 98 * MB);
    u16* Wv  = (u16*)(ws + 100 * MB);
    u16* Wo  = (u16*)(ws + 102 * MB);
    u16* ctx = (u16*)(ws + 48 * MB);   // aliases Xk (dead after QKV projection)

    // 3-ring LDS = 3*(32KB + 16KB) = 144KB > 64KB default: raise the dynamic-LDS cap once.
    static bool attr_done = false;
    if (!attr_done) {
        hipFuncSetAttribute((const void*)gemm_qkv,
                            hipFuncAttributeMaxDynamicSharedMemorySize, 147456);
        hipFuncSetAttribute((const void*)gemm_out,
                            hipFuncAttributeMaxDynamicSharedMemorySize, 147456);
        attr_done = true;
    }

    cast_all<<<14336, 256, 0, stream>>>(keys, queries, values,
                                        (const float*)d_in[4], (const float*)d_in[6],
                                        (const float*)d_in[8], (const float*)d_in[10],
                                        Xk, Xq, Xv, Wk, Wq, Wv, Wo);

    const float kscale = 1.4426950408889634f * 0.125f;  // log2(e)/sqrt(d_key)
    gemm_qkv<<<768, 512, 147456, stream>>>(Xk, Xq, Xv, Wk, Wq, Wv,
                                           WKb, WQb, WVb, Kbh, Qbh, Vtg, kscale);

    attn_kernel<<<512, 256, 0, stream>>>(Kbh, Qbh, Vtg, ctx);

    gemm_out<<<256, 512, 147456, stream>>>(ctx, Wo, WOb, (float*)d_out);
}